// Round 5
// baseline (326.751 us; speedup 1.0000x reference)
//
#include <hip/hip_runtime.h>
#include <hip/hip_bf16.h>
#include <stdint.h>

#define TOKENS 8192
#define NF 4096   // out features
#define KF 4096   // in features
#define RANK 16

typedef __attribute__((ext_vector_type(8))) short bf16x8;
typedef __attribute__((ext_vector_type(4))) float f32x4;
typedef __attribute__((ext_vector_type(16))) float f32x16;
typedef __attribute__((ext_vector_type(8))) unsigned short u16x8;

static __device__ __forceinline__ unsigned short f2b(float f) {
    union { float f; uint32_t u; } v; v.f = f;
    uint32_t u = v.u;
    uint32_t r = (u + 0x7fffu + ((u >> 16) & 1u)) >> 16;   // RNE
    return (unsigned short)r;
}

// Wt[n][k] = bf16( W[k][n] + sum_r U[k][r]*s[r]*Vt[r][n] )  (transposed, K-contiguous)
__global__ __launch_bounds__(256) void prep_w_kernel(
    const float* __restrict__ W, const float* __restrict__ U,
    const float* __restrict__ s, const float* __restrict__ Vt,
    unsigned short* __restrict__ Wt)
{
    __shared__ float Us[64][16];
    __shared__ float Vs[16][64];
    __shared__ float tile[64][65];   // [k][n]
    const int kb = blockIdx.x, nb = blockIdx.y;
    const int t = threadIdx.x;
    for (int idx = t; idx < 64 * 16; idx += 256) {
        int kl = idx >> 4, r = idx & 15;
        Us[kl][r] = U[(size_t)(kb * 64 + kl) * RANK + r];
    }
    for (int idx = t; idx < 16 * 64; idx += 256) {
        int r = idx >> 6, nl = idx & 63;
        Vs[r][nl] = Vt[(size_t)r * NF + nb * 64 + nl] * s[r];
    }
    __syncthreads();
    const int nl = t & 63, kl0 = t >> 6;
    for (int i = 0; i < 16; ++i) {
        int kl = kl0 + i * 4;
        float v = __builtin_nontemporal_load(&W[(size_t)(kb * 64 + kl) * NF + nb * 64 + nl]);
        #pragma unroll
        for (int r = 0; r < RANK; ++r) v += Us[kl][r] * Vs[r][nl];
        tile[kl][nl] = v;
    }
    __syncthreads();
    // vectorized write: 512 items (n, kg); 16B/lane stores, 128B segments
    #pragma unroll
    for (int j = 0; j < 2; ++j) {
        int idx = t + j * 256;
        int kg = idx & 7, n = idx >> 3;
        u16x8 o;
        #pragma unroll
        for (int e = 0; e < 8; ++e) o[e] = f2b(tile[kg * 8 + e][n]);
        *(u16x8*)&Wt[(size_t)(nb * 64 + n) * KF + kb * 64 + kg * 8] = o;
    }
}

__global__ __launch_bounds__(256) void prep_x_kernel(
    const float* __restrict__ x, unsigned short* __restrict__ xb)
{
    size_t base = ((size_t)blockIdx.x * 256 + threadIdx.x) * 8;
    f32x4 a = __builtin_nontemporal_load((const f32x4*)(x + base));
    f32x4 b = __builtin_nontemporal_load((const f32x4*)(x + base + 4));
    u16x8 o;
    o[0] = f2b(a[0]); o[1] = f2b(a[1]); o[2] = f2b(a[2]); o[3] = f2b(a[3]);
    o[4] = f2b(b[0]); o[5] = f2b(b[1]); o[6] = f2b(b[2]); o[7] = f2b(b[3]);
    *(u16x8*)(xb + base) = o;
}

// ---------------------------------------------------------------------------
// 256x256 8-phase GEMM, 32x32x16 MFMA variant.
// A = xb [TOKENS][KF]; Bt = Wt [NF][KF]. 8 waves (2M x 4N), per-wave 128x64.
// LDS 128 KiB = {A,B} x {dbuf} x {half} x [128][64] bf16, XOR swizzle
// (byte ^= (row&7)<<4) via pre-swizzled global source, linear gload_lds dest.
// Round-2-proven stage map (1 stage/phase, even):
//   P1:A-d1 h0(kt1) P2:A-d1 h1(kt1) P3:B-d0 h0(kt2) P4:B-d0 h1(kt2)+VM4
//   P5:A-d0 h0(kt2) P6:A-d0 h1(kt2) P7:B-d1 h0(kt3) P8:B-d1 h1(kt3)+VM4
// Phase q computes M-frag q (32 rows): 4x ds_read_b128 (A, ksteps 0..3),
// then 8x mfma_32x32x16 into acc[q][0..1].
// ---------------------------------------------------------------------------

#define VM4  asm volatile("s_waitcnt vmcnt(4)" ::: "memory")
#define NOVM

#define PHASE(d, q, bfr, STAGE_EXPR, VMW) do {                                  \
    bf16x8 af0 = ldA(d, q, 0), af1 = ldA(d, q, 1);                              \
    bf16x8 af2 = ldA(d, q, 2), af3 = ldA(d, q, 3);                              \
    STAGE_EXPR;                                                                 \
    VMW;                                                                        \
    __builtin_amdgcn_s_barrier();                                               \
    asm volatile("s_waitcnt lgkmcnt(0)" ::: "memory");                          \
    __builtin_amdgcn_s_setprio(1);                                              \
    _Pragma("unroll")                                                           \
    for (int nf = 0; nf < 2; ++nf) {                                            \
        acc[q][nf] = __builtin_amdgcn_mfma_f32_32x32x16_bf16(af0, bfr[nf][0], acc[q][nf], 0,0,0); \
        acc[q][nf] = __builtin_amdgcn_mfma_f32_32x32x16_bf16(af1, bfr[nf][1], acc[q][nf], 0,0,0); \
        acc[q][nf] = __builtin_amdgcn_mfma_f32_32x32x16_bf16(af2, bfr[nf][2], acc[q][nf], 0,0,0); \
        acc[q][nf] = __builtin_amdgcn_mfma_f32_32x32x16_bf16(af3, bfr[nf][3], acc[q][nf], 0,0,0); \
    }                                                                           \
    __builtin_amdgcn_s_setprio(0);                                              \
    __builtin_amdgcn_s_barrier();                                               \
} while (0)

#define LDB_ALL(d, bfr) do {                                                    \
    _Pragma("unroll")                                                           \
    for (int nf = 0; nf < 2; ++nf)                                              \
        _Pragma("unroll")                                                       \
        for (int ks = 0; ks < 4; ++ks)                                          \
            bfr[nf][ks] = ldB(d, nf, ks);                                       \
    } while (0)

__global__ __launch_bounds__(512, 2) void gemm_kernel(
    const unsigned short* __restrict__ A,
    const unsigned short* __restrict__ Bt,
    float* __restrict__ C)
{
    __shared__ __align__(16) unsigned short lds[65536];   // 128 KiB

    const int tid  = threadIdx.x;
    const int lane = tid & 63;
    const int wave = tid >> 6;
    const int wm = wave >> 2;          // 0..1
    const int wn = wave & 3;           // 0..3

    // XCD-aware swizzle: 512 blocks, 512 % 8 == 0 -> bijective
    const int bid = blockIdx.x;
    const int swz = (bid & 7) * 64 + (bid >> 3);
    const int tm = swz >> 4;           // 32 M-tiles
    const int tn = swz & 15;           // 16 N-tiles

    const int l31 = lane & 31;         // fragment row (A) / col (B)
    const int khalf = lane >> 5;       // 0..1 -> k-offset 0/8
    const int xorv = (l31 & 7) << 4;   // read-side byte XOR (bits 4-6)

    // staging: thread tid covers LDS bytes [tid*16, tid*16+16) (+8KB for h=1).
    // source col pre-swizzled with the same involution; LDS dest stays linear.
    const int st_row  = tid >> 3;                                            // 0..63
    const int st_colE = ((((tid & 7) * 16) ^ (((tid >> 3) & 7) << 4)) >> 1); // elems
    const unsigned short* aSrc = A  + (size_t)(tm * 256 + st_row) * KF + st_colE;
    const unsigned short* bSrc = Bt + (size_t)(tn * 256 + st_row) * KF + st_colE;
    const int dstE = tid * 8;

    f32x16 acc[4][2] = {};

    auto stage = [&](int isB, int d, int h, int kt) {
        const unsigned short* src =
            (isB ? bSrc : aSrc) + (size_t)((h) * 128) * KF + (kt) * 64;
        unsigned short* dst = (unsigned short*)&lds[isB * 32768 + (d * 2 + h) * 8192 + dstE];
        __builtin_amdgcn_global_load_lds(
            (const __attribute__((address_space(1))) void*)src,
            (__attribute__((address_space(3))) void*)dst, 16, 0, 0);
        __builtin_amdgcn_global_load_lds(
            (const __attribute__((address_space(1))) void*)(src + (size_t)64 * KF),
            (__attribute__((address_space(3))) void*)(dst + 4096), 16, 0, 0);
    };

    // A frag for 32x32x16: lane holds row=l31 (of 32-row frag q), k=khalf*8+e.
    // byte col = ks*32 + khalf*16, XOR'd by (row&7)<<4 (matches staging swizzle).
    auto ldA = [&](int d, int q, int ks) -> bf16x8 {
        int row = q * 32 + l31;
        int cb  = (ks * 32 + khalf * 16) ^ xorv;
        int off = (d * 2 + wm) * 8192 + row * 64 + (cb >> 1);
        return *(const bf16x8*)&lds[off];
    };
    // B frag: lane holds col n=l31 (of 32-col frag nf), same k mapping; read
    // from Bt rows (n-major, K-contiguous) — symmetric to A.
    auto ldB = [&](int d, int nf, int ks) -> bf16x8 {
        int nrow = (wn & 1) * 64 + nf * 32 + l31;
        int cb   = (ks * 32 + khalf * 16) ^ xorv;
        int off  = 32768 + (d * 2 + (wn >> 1)) * 8192 + nrow * 64 + (cb >> 1);
        return *(const bf16x8*)&lds[off];
    };

    // ---- prologue: B-d0(K0), A-d0(K0), B-d1(K1); drain K0; keep B-d1 in flight
    stage(1, 0, 0, 0); stage(1, 0, 1, 0);
    stage(0, 0, 0, 0); stage(0, 0, 1, 0);
    stage(1, 1, 0, 1); stage(1, 1, 1, 1);
    VM4;
    __builtin_amdgcn_s_barrier();

    // ---- main loop: 64 K-tiles, 2 per iteration ----
    for (int i = 0; i < 32; ++i) {
        const int kt1 = 2 * i + 1;
        const int kt2 = (2 * i + 2) & 63;   // wrap on last iter (dead data, safe)
        const int kt3 = (2 * i + 3) & 63;

        bf16x8 bfr[2][4];
        LDB_ALL(0, bfr);
        PHASE(0, 0, bfr, stage(0, 1, 0, kt1), NOVM);
        PHASE(0, 1, bfr, stage(0, 1, 1, kt1), NOVM);
        PHASE(0, 2, bfr, stage(1, 0, 0, kt2), NOVM);
        PHASE(0, 3, bfr, stage(1, 0, 1, kt2), VM4);
        LDB_ALL(1, bfr);
        PHASE(1, 0, bfr, stage(0, 0, 0, kt2), NOVM);
        PHASE(1, 1, bfr, stage(0, 0, 1, kt2), NOVM);
        PHASE(1, 2, bfr, stage(1, 1, 0, kt3), NOVM);
        PHASE(1, 3, bfr, stage(1, 1, 1, kt3), VM4);
    }

    asm volatile("s_waitcnt vmcnt(0)" ::: "memory");

    // ---- epilogue: 32x32 C/D layout [m74/m101]:
    // col = lane&31, row = (reg&3) + 8*(reg>>2) + 4*(lane>>5)
    #pragma unroll
    for (int q = 0; q < 4; ++q)
        #pragma unroll
        for (int nf = 0; nf < 2; ++nf) {
            size_t col   = (size_t)(tn * 256 + wn * 64 + nf * 32 + l31);
            int    rbase = tm * 256 + wm * 128 + q * 32 + khalf * 4;
            #pragma unroll
            for (int r = 0; r < 16; ++r) {
                int row = rbase + (r & 3) + 8 * (r >> 2);
                C[(size_t)row * NF + col] = acc[q][nf][r];
            }
        }
}

extern "C" void kernel_launch(void* const* d_in, const int* in_sizes, int n_in,
                              void* d_out, int out_size, void* d_ws, size_t ws_size,
                              hipStream_t stream) {
    const float* x  = (const float*)d_in[0];
    const float* W  = (const float*)d_in[1];
    const float* U  = (const float*)d_in[2];
    const float* s  = (const float*)d_in[3];
    const float* Vt = (const float*)d_in[4];
    float* out = (float*)d_out;

    unsigned short* Wt = (unsigned short*)d_ws;                  // 32 MB
    unsigned short* xb = Wt + (size_t)NF * KF;                   // 64 MB

    prep_w_kernel<<<dim3(KF / 64, NF / 64), 256, 0, stream>>>(W, U, s, Vt, Wt);
    prep_x_kernel<<<(TOKENS * KF / 8) / 256, 256, 0, stream>>>(x, xb);
    gemm_kernel<<<(TOKENS / 256) * (NF / 256), 512, 0, stream>>>(xb, Wt, out);
}

// Round 7
// 289.320 us; speedup vs baseline: 1.1294x; 1.1294x over previous
//
#include <hip/hip_runtime.h>
#include <hip/hip_bf16.h>
#include <stdint.h>

#define TOKENS 8192
#define NF 4096   // out features
#define KF 4096   // in features
#define RANK 16

typedef __attribute__((ext_vector_type(8))) short bf16x8;
typedef __attribute__((ext_vector_type(4))) float f32x4;
typedef __attribute__((ext_vector_type(8))) unsigned short u16x8;

static __device__ __forceinline__ unsigned short f2b(float f) {
    union { float f; uint32_t u; } v; v.f = f;
    uint32_t u = v.u;
    uint32_t r = (u + 0x7fffu + ((u >> 16) & 1u)) >> 16;   // RNE
    return (unsigned short)r;
}

// Wt[n][k] = bf16( W[k][n] + sum_r U[k][r]*s[r]*Vt[r][n] )  (transposed, K-contiguous)
__global__ __launch_bounds__(256) void prep_w_kernel(
    const float* __restrict__ W, const float* __restrict__ U,
    const float* __restrict__ s, const float* __restrict__ Vt,
    unsigned short* __restrict__ Wt)
{
    __shared__ float Us[64][16];
    __shared__ float Vs[16][64];
    __shared__ float tile[64][65];   // [k][n]
    const int kb = blockIdx.x, nb = blockIdx.y;
    const int t = threadIdx.x;
    for (int idx = t; idx < 64 * 16; idx += 256) {
        int kl = idx >> 4, r = idx & 15;
        Us[kl][r] = U[(size_t)(kb * 64 + kl) * RANK + r];
    }
    for (int idx = t; idx < 16 * 64; idx += 256) {
        int r = idx >> 6, nl = idx & 63;
        Vs[r][nl] = Vt[(size_t)r * NF + nb * 64 + nl] * s[r];
    }
    __syncthreads();
    const int nl = t & 63, kl0 = t >> 6;
    for (int i = 0; i < 16; ++i) {
        int kl = kl0 + i * 4;
        float v = __builtin_nontemporal_load(&W[(size_t)(kb * 64 + kl) * NF + nb * 64 + nl]);
        #pragma unroll
        for (int r = 0; r < RANK; ++r) v += Us[kl][r] * Vs[r][nl];
        tile[kl][nl] = v;
    }
    __syncthreads();
    // vectorized write: 512 items (n, kg); 16B/lane stores, 128B segments
    #pragma unroll
    for (int j = 0; j < 2; ++j) {
        int idx = t + j * 256;
        int kg = idx & 7, n = idx >> 3;
        u16x8 o;
        #pragma unroll
        for (int e = 0; e < 8; ++e) o[e] = f2b(tile[kg * 8 + e][n]);
        *(u16x8*)&Wt[(size_t)(nb * 64 + n) * KF + kb * 64 + kg * 8] = o;
    }
}

__global__ __launch_bounds__(256) void prep_x_kernel(
    const float* __restrict__ x, unsigned short* __restrict__ xb)
{
    size_t base = ((size_t)blockIdx.x * 256 + threadIdx.x) * 8;
    f32x4 a = __builtin_nontemporal_load((const f32x4*)(x + base));
    f32x4 b = __builtin_nontemporal_load((const f32x4*)(x + base + 4));
    u16x8 o;
    o[0] = f2b(a[0]); o[1] = f2b(a[1]); o[2] = f2b(a[2]); o[3] = f2b(a[3]);
    o[4] = f2b(b[0]); o[5] = f2b(b[1]); o[6] = f2b(b[2]); o[7] = f2b(b[3]);
    *(u16x8*)(xb + base) = o;
}

// ---------------------------------------------------------------------------
// 256x256 8-phase GEMM (round-2 structure) + MFMA-shadow B-register prefetch.
// A = xb [TOKENS][KF]; Bt = Wt [NF][KF]. 8 waves (2M x 4N).
// LDS 128 KiB = {A,B} x {dbuf} x {half} x [128][64] bf16, XOR swizzle
// (byte ^= (row&7)<<4) via pre-swizzled global source, linear gload_lds dest.
// Stage map (round-2-proven):
//   P1:A-d1 h0(kt1) P2:A-d1 h1(kt1) P3:B-d0 h0(kt2) P4:B-d0 h1(kt2)+VM4
//   P5:A-d0 h0(kt2) P6:A-d0 h1(kt2) P7:B-d1 h0(kt3) P8:B-d1 h1(kt3)+VM4
// B-reg prefetch (race-free, unlike round-5): the 8 ds_read_b128 for the
// NEXT d-group are issued in P4/P8 *after the opening barrier* (all waves
// have passed their VM4, which retires exactly that B-region -> fully
// visible), inside the setprio/MFMA shadow. They drain at the next phase's
// lgkmcnt(0). Hoist above the barrier is blocked by the lgkmcnt(0)
// memory-clobber asm; sinking merely degenerates to round-2 behavior.
// ---------------------------------------------------------------------------

#define VM4  asm volatile("s_waitcnt vmcnt(4)" ::: "memory")

#define MFMA16(q, bfr) do {                                                     \
    _Pragma("unroll")                                                           \
    for (int nf = 0; nf < 4; ++nf) {                                            \
        acc[2*(q)][nf]   = __builtin_amdgcn_mfma_f32_16x16x32_bf16(af0k0, bfr[nf][0], acc[2*(q)][nf],   0,0,0); \
        acc[2*(q)][nf]   = __builtin_amdgcn_mfma_f32_16x16x32_bf16(af0k1, bfr[nf][1], acc[2*(q)][nf],   0,0,0); \
        acc[2*(q)+1][nf] = __builtin_amdgcn_mfma_f32_16x16x32_bf16(af1k0, bfr[nf][0], acc[2*(q)+1][nf], 0,0,0); \
        acc[2*(q)+1][nf] = __builtin_amdgcn_mfma_f32_16x16x32_bf16(af1k1, bfr[nf][1], acc[2*(q)+1][nf], 0,0,0); \
    } } while (0)

#define LDB_ALL(d, bfr) do {                                                    \
    _Pragma("unroll")                                                           \
    for (int nf = 0; nf < 4; ++nf) {                                            \
        bfr[nf][0] = ldB(d, nf, 0);                                             \
        bfr[nf][1] = ldB(d, nf, 1);                                             \
    } } while (0)

#define PHASE(d, q, bfr, STAGE_EXPR) do {                                       \
    bf16x8 af0k0 = ldA(d, 2*(q), 0),   af0k1 = ldA(d, 2*(q), 1);                \
    bf16x8 af1k0 = ldA(d, 2*(q)+1, 0), af1k1 = ldA(d, 2*(q)+1, 1);              \
    STAGE_EXPR;                                                                 \
    __builtin_amdgcn_s_barrier();                                               \
    asm volatile("s_waitcnt lgkmcnt(0)" ::: "memory");                          \
    __builtin_amdgcn_s_setprio(1);                                              \
    MFMA16(q, bfr);                                                             \
    __builtin_amdgcn_s_setprio(0);                                              \
    __builtin_amdgcn_s_barrier();                                               \
} while (0)

// checkpoint phase: stage, VM4, barrier, then prefetch next B-set in MFMA shadow
#define PHASEX(d, q, bfr, bnxt, dnxt, STAGE_EXPR) do {                          \
    bf16x8 af0k0 = ldA(d, 2*(q), 0),   af0k1 = ldA(d, 2*(q), 1);                \
    bf16x8 af1k0 = ldA(d, 2*(q)+1, 0), af1k1 = ldA(d, 2*(q)+1, 1);              \
    STAGE_EXPR;                                                                 \
    VM4;                                                                        \
    __builtin_amdgcn_s_barrier();                                               \
    asm volatile("s_waitcnt lgkmcnt(0)" ::: "memory");                          \
    __builtin_amdgcn_s_setprio(1);                                              \
    LDB_ALL(dnxt, bnxt);                                                        \
    MFMA16(q, bfr);                                                             \
    __builtin_amdgcn_s_setprio(0);                                              \
    __builtin_amdgcn_s_barrier();                                               \
} while (0)

__global__ __launch_bounds__(512, 2) void gemm_kernel(
    const unsigned short* __restrict__ A,
    const unsigned short* __restrict__ Bt,
    float* __restrict__ C)
{
    __shared__ __align__(16) unsigned short lds[65536];   // 128 KiB

    const int tid  = threadIdx.x;
    const int lane = tid & 63;
    const int wave = tid >> 6;
    const int wm = wave >> 2;          // 0..1
    const int wn = wave & 3;           // 0..3

    // XCD-aware swizzle: 512 blocks, 512 % 8 == 0 -> bijective
    const int bid = blockIdx.x;
    const int swz = (bid & 7) * 64 + (bid >> 3);
    const int tm = swz >> 4;           // 32 M-tiles
    const int tn = swz & 15;           // 16 N-tiles

    const int frow = lane & 15;
    const int kgrp = lane >> 4;
    const int xorv = (frow & 7) << 4;  // read-side byte XOR (bits 4-6)

    // staging: thread tid covers LDS bytes [tid*16, tid*16+16) (+8KB for h=1).
    // source col pre-swizzled with the same involution; LDS dest stays linear.
    const int st_row  = tid >> 3;                                            // 0..63
    const int st_colE = ((((tid & 7) * 16) ^ (((tid >> 3) & 7) << 4)) >> 1); // elems
    const unsigned short* aSrc = A  + (size_t)(tm * 256 + st_row) * KF + st_colE;
    const unsigned short* bSrc = Bt + (size_t)(tn * 256 + st_row) * KF + st_colE;
    const int dstE = tid * 8;

    f32x4 acc[8][4] = {};

    auto stage = [&](int isB, int d, int h, int kt) {
        const unsigned short* src =
            (isB ? bSrc : aSrc) + (size_t)((h) * 128) * KF + (kt) * 64;
        unsigned short* dst = (unsigned short*)&lds[isB * 32768 + (d * 2 + h) * 8192 + dstE];
        __builtin_amdgcn_global_load_lds(
            (const __attribute__((address_space(1))) void*)src,
            (__attribute__((address_space(3))) void*)dst, 16, 0, 0);
        __builtin_amdgcn_global_load_lds(
            (const __attribute__((address_space(1))) void*)(src + (size_t)64 * KF),
            (__attribute__((address_space(3))) void*)(dst + 4096), 16, 0, 0);
    };

    auto ldA = [&](int d, int mf, int kk) -> bf16x8 {
        int off = (d * 2 + wm) * 8192 + (mf * 16 + frow) * 64
                + ((((kk << 6) | (kgrp << 4)) ^ xorv) >> 1);
        return *(const bf16x8*)&lds[off];
    };
    auto ldB = [&](int d, int nf, int kk) -> bf16x8 {
        int off = 32768 + (d * 2 + (wn >> 1)) * 8192
                + ((wn & 1) * 64 + nf * 16 + frow) * 64
                + ((((kk << 6) | (kgrp << 4)) ^ xorv) >> 1);
        return *(const bf16x8*)&lds[off];
    };

    bf16x8 bfrP[4][2], bfrQ[4][2];

    // ---- prologue: B-d0(K0), A-d0(K0), B-d1(K1); VM4 retires B-d0+A-d0
    // (FIFO), leaving B-d1 in flight = steady-state carry. After the barrier
    // all waves' B-d0 writes are visible -> load bfrP.
    stage(1, 0, 0, 0); stage(1, 0, 1, 0);
    stage(0, 0, 0, 0); stage(0, 0, 1, 0);
    stage(1, 1, 0, 1); stage(1, 1, 1, 1);
    VM4;
    __builtin_amdgcn_s_barrier();
    asm volatile("" ::: "memory");     // keep bfrP reads below the barrier
    LDB_ALL(0, bfrP);

    // ---- main loop: 64 K-tiles, 2 per iteration ----
    for (int i = 0; i < 32; ++i) {
        const int kt1 = 2 * i + 1;
        const int kt2 = (2 * i + 2) & 63;   // wrap on last iter (dead data, safe)
        const int kt3 = (2 * i + 3) & 63;

        PHASE (0, 0, bfrP, stage(0, 1, 0, kt1));
        PHASE (0, 1, bfrP, stage(0, 1, 1, kt1));
        PHASE (0, 2, bfrP, stage(1, 0, 0, kt2));
        PHASEX(0, 3, bfrP, bfrQ, 1, stage(1, 0, 1, kt2));   // VM4 retires B-d1(kt1): bfrQ <- B-d1
        PHASE (1, 0, bfrQ, stage(0, 0, 0, kt2));
        PHASE (1, 1, bfrQ, stage(0, 0, 1, kt2));
        PHASE (1, 2, bfrQ, stage(1, 1, 0, kt3));
        PHASEX(1, 3, bfrQ, bfrP, 0, stage(1, 1, 1, kt3));   // VM4 retires B-d0(kt2): bfrP <- B-d0
    }

    asm volatile("s_waitcnt vmcnt(0)" ::: "memory");

    // ---- epilogue: C/D layout col=lane&15, row=(lane>>4)*4+reg ----
    const int rgrp = lane >> 4, coll = lane & 15;
    #pragma unroll
    for (int mf = 0; mf < 8; ++mf)
        #pragma unroll
        for (int nf = 0; nf < 4; ++nf) {
            size_t row0 = (size_t)(tm * 256 + wm * 128 + mf * 16 + rgrp * 4);
            size_t col  = (size_t)(tn * 256 + wn * 64 + nf * 16 + coll);
            #pragma unroll
            for (int r = 0; r < 4; ++r)
                C[(row0 + r) * NF + col] = acc[mf][nf][r];
        }
}

extern "C" void kernel_launch(void* const* d_in, const int* in_sizes, int n_in,
                              void* d_out, int out_size, void* d_ws, size_t ws_size,
                              hipStream_t stream) {
    const float* x  = (const float*)d_in[0];
    const float* W  = (const float*)d_in[1];
    const float* U  = (const float*)d_in[2];
    const float* s  = (const float*)d_in[3];
    const float* Vt = (const float*)d_in[4];
    float* out = (float*)d_out;

    unsigned short* Wt = (unsigned short*)d_ws;                  // 32 MB
    unsigned short* xb = Wt + (size_t)NF * KF;                   // 64 MB

    prep_w_kernel<<<dim3(KF / 64, NF / 64), 256, 0, stream>>>(W, U, s, Vt, Wt);
    prep_x_kernel<<<(TOKENS * KF / 8) / 256, 256, 0, stream>>>(x, xb);
    gemm_kernel<<<(TOKENS / 256) * (NF / 256), 512, 0, stream>>>(xb, Wt, out);
}